// Round 10
// baseline (225.529 us; speedup 1.0000x reference)
//
#include <hip/hip_runtime.h>

// HTMM: C=32 states, L=4 fanout, M=128 symbols, DEPTH=7.
// Level starts: {0,1,5,21,85,341,1365,5461,21845}.
// SINGLE kernel, 256 blocks x 256 threads, one block per level-4 subtree.
// R10: distributed top-tree (R9 algorithm) with register discipline:
//   - transition to down tables happens BEFORE the owner duties; duties use
//     the DOWN-oriented Wr (lane=j) via partial+LDS-transpose, so up-Wr and
//     down-Wr live ranges never overlap (R9's spill cause).
//   - block 85's top-down uses unpaired wu128 (lower pressure in the fattest
//     code region; it is one block's tail).
// All sync is write-once MAGIC flags (!= 0xAA poison) -> no memset dispatch.

static constexpr int OFF_B4   = 0;      // level-4 betas [s*32+i] (8192 f)
static constexpr int OFF_TB   = 8192;   // top t_beta [node*32+i], 85 nodes (2720 f)
static constexpr int OFF_PART = 10912;  // 256 doubles (512 f, 8B-aligned)
static constexpr int IFLAGA   = 11424;  // 256 flags: b4 ready
static constexpr int IFLAGT   = 11680;  // 85 flags: TB[node] ready
static constexpr int IFLAGF   = 11776;  // 256 flags: partial ready
static constexpr int MAGIC    = 0x5CA1AB1E;

__device__ __forceinline__ void st_flag(int* p) {
  __hip_atomic_store(p, MAGIC, __ATOMIC_RELEASE, __HIP_MEMORY_SCOPE_AGENT);
}
__device__ __forceinline__ void wait_flag(int* p) {
  while (__hip_atomic_load(p, __ATOMIC_ACQUIRE, __HIP_MEMORY_SCOPE_AGENT) != MAGIC)
    __builtin_amdgcn_s_sleep(1);
}

__device__ __forceinline__ float rsum32(float v) {
#pragma unroll
  for (int k = 1; k <= 16; k <<= 1) v += __shfl_xor(v, k);
  return v;
}
__device__ __forceinline__ void rsum32x2(float& a, float& b) {
#pragma unroll
  for (int k = 1; k <= 16; k <<= 1) { a += __shfl_xor(a, k); b += __shfl_xor(b, k); }
}
__device__ __forceinline__ void rsum32x4(float& a, float& b, float& c, float& d) {
#pragma unroll
  for (int k = 1; k <= 16; k <<= 1) {
    a += __shfl_xor(a, k); b += __shfl_xor(b, k);
    c += __shfl_xor(c, k); d += __shfl_xor(d, k);
  }
}
__device__ __forceinline__ float4 exp4f(float4 v) {
  return make_float4(__expf(v.x), __expf(v.y), __expf(v.z), __expf(v.w));
}

__device__ __forceinline__ float dot128(const float* Wr, const float* X) {
  float t0 = 0.f, t1 = 0.f, t2 = 0.f, t3 = 0.f;
#pragma unroll
  for (int j = 0; j < 32; ++j) {
    const float4 x = *(const float4*)(X + j * 4);
    t0 = fmaf(Wr[4 * j + 0], x.x, t0);
    t1 = fmaf(Wr[4 * j + 1], x.y, t1);
    t2 = fmaf(Wr[4 * j + 2], x.z, t2);
    t3 = fmaf(Wr[4 * j + 3], x.w, t3);
  }
  return (t0 + t1) + (t2 + t3);
}
__device__ __forceinline__ void dot128x2(const float* Wr, const float* X0,
                                         const float* X1, float& o0, float& o1) {
  float a0 = 0.f, a1 = 0.f, a2 = 0.f, a3 = 0.f;
  float b0 = 0.f, b1 = 0.f, b2 = 0.f, b3 = 0.f;
#pragma unroll
  for (int j = 0; j < 32; ++j) {
    const float4 x = *(const float4*)(X0 + j * 4);
    const float4 y = *(const float4*)(X1 + j * 4);
    a0 = fmaf(Wr[4 * j + 0], x.x, a0); b0 = fmaf(Wr[4 * j + 0], y.x, b0);
    a1 = fmaf(Wr[4 * j + 1], x.y, a1); b1 = fmaf(Wr[4 * j + 1], y.y, b1);
    a2 = fmaf(Wr[4 * j + 2], x.z, a2); b2 = fmaf(Wr[4 * j + 2], y.z, b2);
    a3 = fmaf(Wr[4 * j + 3], x.w, a3); b3 = fmaf(Wr[4 * j + 3], y.w, b3);
  }
  o0 = (a0 + a1) + (a2 + a3);
  o1 = (b0 + b1) + (b2 + b3);
}

__device__ __forceinline__ void wu128(const float* Wr, const float* ALG,
                                      const float* rb, int lane,
                                      float w[4], float u[4]) {
  w[0] = w[1] = w[2] = w[3] = 0.f;
  u[0] = u[1] = u[2] = u[3] = 0.f;
#pragma unroll
  for (int ii = 0; ii < 32; ii += 4) {
    const float4 rv = *(const float4*)(rb + ii);
#pragma unroll
    for (int di = 0; di < 4; ++di) {
      const int i = ii + di;
      const float rr = (di == 0) ? rv.x : (di == 1) ? rv.y : (di == 2) ? rv.z : rv.w;
      const float4 av = *(const float4*)(ALG + i * 128 + lane * 4);
      w[0] = fmaf(Wr[i * 4 + 0], rr, w[0]); u[0] = fmaf(av.x, rr, u[0]);
      w[1] = fmaf(Wr[i * 4 + 1], rr, w[1]); u[1] = fmaf(av.y, rr, u[1]);
      w[2] = fmaf(Wr[i * 4 + 2], rr, w[2]); u[2] = fmaf(av.z, rr, u[2]);
      w[3] = fmaf(Wr[i * 4 + 3], rr, w[3]); u[3] = fmaf(av.w, rr, u[3]);
    }
  }
}
__device__ __forceinline__ void wu128x2(const float* Wr, const float* ALG,
                                        const float* rb0, const float* rb1, int lane,
                                        float w0[4], float u0[4],
                                        float w1[4], float u1[4]) {
#pragma unroll
  for (int l = 0; l < 4; ++l) { w0[l] = u0[l] = w1[l] = u1[l] = 0.f; }
#pragma unroll
  for (int ii = 0; ii < 32; ii += 4) {
    const float4 r0 = *(const float4*)(rb0 + ii);
    const float4 r1 = *(const float4*)(rb1 + ii);
#pragma unroll
    for (int di = 0; di < 4; ++di) {
      const int i = ii + di;
      const float q0 = (di == 0) ? r0.x : (di == 1) ? r0.y : (di == 2) ? r0.z : r0.w;
      const float q1 = (di == 0) ? r1.x : (di == 1) ? r1.y : (di == 2) ? r1.z : r1.w;
      const float4 av = *(const float4*)(ALG + i * 128 + lane * 4);
      w0[0] = fmaf(Wr[i * 4 + 0], q0, w0[0]); w1[0] = fmaf(Wr[i * 4 + 0], q1, w1[0]);
      u0[0] = fmaf(av.x, q0, u0[0]);          u1[0] = fmaf(av.x, q1, u1[0]);
      w0[1] = fmaf(Wr[i * 4 + 1], q0, w0[1]); w1[1] = fmaf(Wr[i * 4 + 1], q1, w1[1]);
      u0[1] = fmaf(av.y, q0, u0[1]);          u1[1] = fmaf(av.y, q1, u1[1]);
      w0[2] = fmaf(Wr[i * 4 + 2], q0, w0[2]); w1[2] = fmaf(Wr[i * 4 + 2], q1, w1[2]);
      u0[2] = fmaf(av.z, q0, u0[2]);          u1[2] = fmaf(av.z, q1, u1[2]);
      w0[3] = fmaf(Wr[i * 4 + 3], q0, w0[3]); w1[3] = fmaf(Wr[i * 4 + 3], q1, w1[3]);
      u0[3] = fmaf(av.w, q0, u0[3]);          u1[3] = fmaf(av.w, q1, u1[3]);
    }
  }
}
__device__ __forceinline__ void wonly128(const float* Wr, const float* rb,
                                         float w[4]) {
  w[0] = w[1] = w[2] = w[3] = 0.f;
#pragma unroll
  for (int ii = 0; ii < 32; ii += 4) {
    const float4 rv = *(const float4*)(rb + ii);
#pragma unroll
    for (int di = 0; di < 4; ++di) {
      const int i = ii + di;
      const float rr = (di == 0) ? rv.x : (di == 1) ? rv.y : (di == 2) ? rv.z : rv.w;
      w[0] = fmaf(Wr[i * 4 + 0], rr, w[0]);
      w[1] = fmaf(Wr[i * 4 + 1], rr, w[1]);
      w[2] = fmaf(Wr[i * 4 + 2], rr, w[2]);
      w[3] = fmaf(Wr[i * 4 + 3], rr, w[3]);
    }
  }
}

__global__ __launch_bounds__(256, 1) void k_fused(const int* __restrict__ labels,
                                                  const float* __restrict__ A,
                                                  const float* __restrict__ B,
                                                  const float* __restrict__ Pi,
                                                  const float* __restrict__ SP,
                                                  float* __restrict__ ws,
                                                  float* __restrict__ out) {
  __shared__ __align__(16) float scr[4224];
  __shared__ __align__(16) float regB[4224];
  __shared__ __align__(16) float sPt[132];
  __shared__ __align__(16) float tbrT[2720];  // duty transpose scratch / blk-85 TB
  __shared__ __align__(16) float tbS[672];
  __shared__ __align__(16) float ownb[32];
  __shared__ __align__(16) float e4buf[32];
  __shared__ __align__(16) float r_buf[512];
  __shared__ int labs[425];
  const int t = threadIdx.x, lane = t & 31, grp = t >> 5;  // 8 groups
  const int s = blockIdx.x;
  int* wsi = (int*)ws;
  double* partd = (double*)(ws + OFF_PART);
  const float4* A4 = (const float4*)A;
  const float4* B4 = (const float4*)B;

  // ---------- phase 1: softmax tables ----------
  const float sv0 = SP[0], sv1 = SP[1], sv2 = SP[2], sv3 = SP[3];
  const float sp0 = __expf(sv0), sp1 = __expf(sv1), sp2 = __expf(sv2), sp3 = __expf(sv3);
  const float spsum = sp0 + sp1 + sp2 + sp3;
  const float spinv = 1.f / spsum;
  const float lss = __logf(spsum);
  float4 c4 = make_float4(0.f, 0.f, 0.f, 0.f);
  for (int i = 0; i < 32; ++i) {
    const float4 e = exp4f(A4[i * 32 + lane]);
    c4.x += e.x; c4.y += e.y; c4.z += e.z; c4.w += e.w;
  }
  const float4 inv4 = make_float4(sp0 * spinv / c4.x, sp1 * spinv / c4.y,
                                  sp2 * spinv / c4.z, sp3 * spinv / c4.w);
  const float4 sub4 = make_float4(__logf(c4.x) - (sv0 - lss), __logf(c4.y) - (sv1 - lss),
                                  __logf(c4.z) - (sv2 - lss), __logf(c4.w) - (sv3 - lss));
#pragma unroll
  for (int k = 0; k < 4; ++k) {  // asp (up layout, stride 132)
    const int i = grp * 4 + k;
    const float4 e = exp4f(A4[i * 32 + lane]);
    *(float4*)(scr + i * 132 + 4 * lane) =
        make_float4(e.x * inv4.x, e.y * inv4.y, e.z * inv4.z, e.w * inv4.w);
  }
#pragma unroll
  for (int rI = 0; rI < 4; ++rI) {  // smB^T
    const int i = grp + rI * 8;
    const float4 e = exp4f(B4[i * 32 + lane]);
    const float sinv = 1.f / rsum32(e.x + e.y + e.z + e.w);
    regB[(4 * lane + 0) * 33 + i] = e.x * sinv;
    regB[(4 * lane + 1) * 33 + i] = e.y * sinv;
    regB[(4 * lane + 2) * 33 + i] = e.z * sinv;
    regB[(4 * lane + 3) * 33 + i] = e.w * sinv;
  }
  if (grp < 4) {  // smPi^T
    const float e = __expf(Pi[lane * 4 + grp]);
    sPt[grp * 33 + lane] = e / rsum32(e);
  }
  for (int idx = t; idx < 341; idx += 256) labs[idx] = labels[idx];
  if (t < 84) {
    int g, d;
    if (t < 4) { g = 341 + 4 * s + t; d = 341 + t; }
    else if (t < 20) { g = 1365 + 16 * s + (t - 4); d = 345 + (t - 4); }
    else { g = 5461 + 64 * s + (t - 20); d = 361 + (t - 20); }
    labs[d] = labels[g];
  }
  __syncthreads();
  float Wr[128];  // up orientation: lane = state i; Wr[4j+l] = ASP[i,j,l]
#pragma unroll
  for (int j = 0; j < 32; ++j) {
    const float4 v = *(const float4*)(scr + lane * 132 + j * 4);
    Wr[4 * j] = v.x; Wr[4 * j + 1] = v.y; Wr[4 * j + 2] = v.z; Wr[4 * j + 3] = v.w;
  }
  __syncthreads();

  // ---------- phase 2: subtree up sweep (last use of up-Wr) ----------
#pragma unroll
  for (int h = 0; h < 2; ++h) {  // S1: 64 leaves, batches of 4
    const int q0 = grp + 32 * h, q1 = q0 + 8, q2 = q0 + 16, q3 = q0 + 24;
    float v0 = sPt[(q0 & 3) * 33 + lane] * regB[labs[361 + q0] * 33 + lane];
    float v1 = sPt[(q1 & 3) * 33 + lane] * regB[labs[361 + q1] * 33 + lane];
    float v2 = sPt[(q2 & 3) * 33 + lane] * regB[labs[361 + q2] * 33 + lane];
    float v3 = sPt[(q3 & 3) * 33 + lane] * regB[labs[361 + q3] * 33 + lane];
    float s0 = v0, s1 = v1, s2 = v2, s3 = v3;
    rsum32x4(s0, s1, s2, s3);
    scr[(q0 >> 2) * 128 + lane * 4 + (q0 & 3)] = v0 / s0;
    scr[(q1 >> 2) * 128 + lane * 4 + (q1 & 3)] = v1 / s1;
    scr[(q2 >> 2) * 128 + lane * 4 + (q2 & 3)] = v2 / s2;
    scr[(q3 >> 2) * 128 + lane * 4 + (q3 & 3)] = v3 / s3;
  }
  __syncthreads();
  {  // S2: 16 L6 parents, paired
    const int p0 = grp, p1 = grp + 8;
    float tb0, tb1;
    dot128x2(Wr, scr + p0 * 128, scr + p1 * 128, tb0, tb1);
    float bl0 = tb0 * regB[labs[345 + p0] * 33 + lane];
    float bl1 = tb1 * regB[labs[345 + p1] * 33 + lane];
    float s0 = bl0, s1 = bl1;
    rsum32x2(s0, s1);
    bl0 /= s0; bl1 /= s1;
    tbS[(5 + p0) * 32 + lane] = tb0;
    tbS[(5 + p1) * 32 + lane] = tb1;
    scr[2048 + (p0 >> 2) * 128 + lane * 4 + (p0 & 3)] = bl0;  // X6
    scr[2048 + (p1 >> 2) * 128 + lane * 4 + (p1 & 3)] = bl1;
  }
  __syncthreads();
  if (grp < 4) {  // S3: 4 L5 parents
    const float tb = dot128(Wr, scr + 2048 + grp * 128);
    float bl = tb * regB[labs[341 + grp] * 33 + lane];
    bl /= rsum32(bl);
    tbS[(1 + grp) * 32 + lane] = tb;
    scr[2560 + lane * 4 + grp] = bl;  // X5
  }
  __syncthreads();
  if (grp == 0) {  // S4: own level-4 root; publish b4
    const float tb = dot128(Wr, scr + 2560);
    float bl = tb * regB[labs[85 + s] * 33 + lane];
    bl /= rsum32(bl);
    tbS[lane] = tb;
    ownb[lane] = bl;
    ws[OFF_B4 + s * 32 + lane] = bl;
  }
  __syncthreads();
  if (t == 0) {
    __threadfence();
    st_flag(&wsi[IFLAGA + s]);
  }
  // (up-Wr is DEAD from here on)

  // ---------- phase 3: transition to down tables ----------
  for (int idx = t; idx < 4224; idx += 256) regB[idx] = __logf(regB[idx]);
  if (t < 132) sPt[t] = __logf(sPt[t]);
#pragma unroll
  for (int i = 0; i < 32; ++i) {  // Wr -> down orient (lane=j); scr -> ALG
    const float4 av = A4[i * 32 + lane];
    const float4 e = exp4f(av);
    const float4 asp = make_float4(e.x * inv4.x, e.y * inv4.y, e.z * inv4.z, e.w * inv4.w);
    Wr[i * 4 + 0] = asp.x; Wr[i * 4 + 1] = asp.y;
    Wr[i * 4 + 2] = asp.z; Wr[i * 4 + 3] = asp.w;
    if (grp == (i >> 2))
      *(float4*)(scr + i * 128 + lane * 4) =
          make_float4(asp.x * (av.x - sub4.x), asp.y * (av.y - sub4.y),
                      asp.z * (av.z - sub4.z), asp.w * (av.w - sub4.w));
  }
  __syncthreads();

  // ---------- distributed top-up duties (owners, down-orient, lane=j) ----------
  if (s < 85) {
    int outn, chb = 0;
    const bool isL3 = (s < 64);
    if (isL3) outn = 21 + s;
    else if (s < 80) { outn = 5 + (s - 64); chb = 21 + 4 * (s - 64); }
    else if (s < 84) { outn = 1 + (s - 80); chb = 5 + 4 * (s - 80); }
    else { outn = 0; chb = 1; }
    if (isL3) { if (t < 4) wait_flag(&wsi[IFLAGA + 4 * s + t]); }
    else      { if (t < 4) wait_flag(&wsi[IFLAGT + chb + t]); }
    __syncthreads();
    __threadfence();
    if (grp == 0) {
      float bc[4];
      if (isL3) {
#pragma unroll
        for (int l = 0; l < 4; ++l) bc[l] = ws[OFF_B4 + (4 * s + l) * 32 + lane];
      } else {
        float v0 = ws[OFF_TB + (chb + 0) * 32 + lane] * __expf(regB[labs[chb + 0] * 33 + lane]);
        float v1 = ws[OFF_TB + (chb + 1) * 32 + lane] * __expf(regB[labs[chb + 1] * 33 + lane]);
        float v2 = ws[OFF_TB + (chb + 2) * 32 + lane] * __expf(regB[labs[chb + 2] * 33 + lane]);
        float v3 = ws[OFF_TB + (chb + 3) * 32 + lane] * __expf(regB[labs[chb + 3] * 33 + lane]);
        float s0 = v0, s1 = v1, s2 = v2, s3 = v3;
        rsum32x4(s0, s1, s2, s3);
        bc[0] = v0 / s0; bc[1] = v1 / s1; bc[2] = v2 / s2; bc[3] = v3 / s3;
      }
      // partials: lane=j computes p_i = sum_l Wr[i*4+l]*bc[l]; transpose via LDS
#pragma unroll
      for (int c = 0; c < 4; ++c) {
#pragma unroll
        for (int ii = 0; ii < 8; ++ii) {
          const int i = c * 8 + ii;
          const float p = fmaf(Wr[i * 4 + 0], bc[0],
                          fmaf(Wr[i * 4 + 1], bc[1],
                           fmaf(Wr[i * 4 + 2], bc[2], Wr[i * 4 + 3] * bc[3])));
          tbrT[i * 33 + lane] = p;  // row i, col j=lane (conflict-free)
        }
      }
      // same-wave write->read; row sum (conflict-free: bank = (lane+k)%32)
      float a0 = 0.f, a1 = 0.f, a2 = 0.f, a3 = 0.f;
#pragma unroll
      for (int k = 0; k < 32; k += 4) {
        a0 += tbrT[lane * 33 + k];     a1 += tbrT[lane * 33 + k + 1];
        a2 += tbrT[lane * 33 + k + 2]; a3 += tbrT[lane * 33 + k + 3];
      }
      ws[OFF_TB + outn * 32 + lane] = (a0 + a1) + (a2 + a3);
    }
    __syncthreads();
    if (t == 0) { __threadfence(); st_flag(&wsi[IFLAGT + outn]); }
  }

  // ---------- wait for top-up complete (one flag; chain implies the rest) ----------
  if (t == 0) wait_flag(&wsi[IFLAGT + 0]);
  __syncthreads();
  __threadfence();

  // ---------- phase 5: top down ----------
  double ll = 0.0;
  float eps4own = 0.f;  // valid in grp 0 (non-85 blocks)
  if (s == 85) {
    // full top-down with ll terms (this block only; unpaired for low pressure)
    for (int idx = t; idx < 2720; idx += 256) tbrT[idx] = ws[OFF_TB + idx];
    __syncthreads();
    if (grp == 0) {  // D0: root
      const float tb0 = tbrT[lane];
      float bc = tb0 * __expf(regB[labs[0] * 33 + lane]);
      bc /= rsum32(bc);
      ll += (double)(bc * regB[labs[0] * 33 + lane]);
      r_buf[lane] = bc / tb0;
      float w[4], u[4];
      wu128(Wr, scr, r_buf, lane, w, u);
#pragma unroll
      for (int l = 0; l < 4; ++l) {
        const int cl = 1 + l;
        const float tbv = tbrT[cl * 32 + lane];
        float bcv = tbv * __expf(regB[labs[cl] * 33 + lane]);
        bcv /= rsum32(bcv);
        const float e = bcv * w[l];
        ll += (double)(bcv * u[l]) + (double)(e * regB[labs[cl] * 33 + lane]);
        tbrT[cl * 32 + lane] = e / tbv;
      }
    }
    __syncthreads();
    if (grp < 4) {  // D1: 4 L1 parents
      const int p = grp;
      r_buf[p * 32 + lane] = tbrT[(1 + p) * 32 + lane];
      float w[4], u[4];
      wu128(Wr, scr, r_buf + p * 32, lane, w, u);
#pragma unroll
      for (int l = 0; l < 4; ++l) {
        const int cl = 5 + p * 4 + l;
        const float tbv = tbrT[cl * 32 + lane];
        float bcv = tbv * __expf(regB[labs[cl] * 33 + lane]);
        bcv /= rsum32(bcv);
        const float e = bcv * w[l];
        ll += (double)(bcv * u[l]) + (double)(e * regB[labs[cl] * 33 + lane]);
        tbrT[cl * 32 + lane] = e / tbv;
      }
    }
    __syncthreads();
    for (int p = grp; p < 16; p += 8) {  // D2: 16 L2 parents
      r_buf[grp * 32 + lane] = tbrT[(5 + p) * 32 + lane];
      float w[4], u[4];
      wu128(Wr, scr, r_buf + grp * 32, lane, w, u);
#pragma unroll
      for (int l = 0; l < 4; ++l) {
        const int cl = 21 + p * 4 + l;
        const float tbv = tbrT[cl * 32 + lane];
        float bcv = tbv * __expf(regB[labs[cl] * 33 + lane]);
        bcv /= rsum32(bcv);
        const float e = bcv * w[l];
        ll += (double)(bcv * u[l]) + (double)(e * regB[labs[cl] * 33 + lane]);
        tbrT[cl * 32 + lane] = e / tbv;
      }
    }
    __syncthreads();
    for (int p = grp; p < 64; p += 8) {  // D3: 64 L3 parents; children = b4
      r_buf[grp * 32 + lane] = tbrT[(21 + p) * 32 + lane];
      float w[4], u[4];
      wu128(Wr, scr, r_buf + grp * 32, lane, w, u);
#pragma unroll
      for (int l = 0; l < 4; ++l) {
        const int ci = p * 4 + l;
        const float bcv = ws[OFF_B4 + ci * 32 + lane];
        const float e = bcv * w[l];
        ll += (double)(bcv * u[l]) + (double)(e * regB[labs[85 + ci] * 33 + lane]);
        if (ci == 85) e4buf[lane] = e;  // own (s=85) level-4 eps
      }
    }
    __syncthreads();
  } else {
    // path-only walk (all groups redundantly; TB from global)
    const int n1 = 1 + (s >> 6), n2 = 5 + (s >> 4), n3 = 21 + (s >> 2);
    const int a0 = s >> 6, a1 = (s >> 4) & 3, a2 = (s >> 2) & 3, a3 = s & 3;
    float w[4];
    float tbv = ws[OFF_TB + lane];
    float bcv = tbv * __expf(regB[labs[0] * 33 + lane]);
    bcv /= rsum32(bcv);
    float r = bcv / tbv;
    r_buf[grp * 32 + lane] = r;
    wonly128(Wr, r_buf + grp * 32, w);
    tbv = ws[OFF_TB + n1 * 32 + lane];
    bcv = tbv * __expf(regB[labs[n1] * 33 + lane]);
    bcv /= rsum32(bcv);
    r = (bcv * w[a0]) / tbv;
    r_buf[grp * 32 + lane] = r;
    wonly128(Wr, r_buf + grp * 32, w);
    tbv = ws[OFF_TB + n2 * 32 + lane];
    bcv = tbv * __expf(regB[labs[n2] * 33 + lane]);
    bcv /= rsum32(bcv);
    r = (bcv * w[a1]) / tbv;
    r_buf[grp * 32 + lane] = r;
    wonly128(Wr, r_buf + grp * 32, w);
    tbv = ws[OFF_TB + n3 * 32 + lane];
    bcv = tbv * __expf(regB[labs[n3] * 33 + lane]);
    bcv /= rsum32(bcv);
    r = (bcv * w[a2]) / tbv;
    r_buf[grp * 32 + lane] = r;
    wonly128(Wr, r_buf + grp * 32, w);
    eps4own = ownb[lane] * w[a3];
    __syncthreads();
  }

  // ---------- phase 6: subtree down sweep ----------
  if (grp == 0) {  // d0: own L4 node -> L5 children
    const float e4 = (s == 85) ? e4buf[lane] : eps4own;
    r_buf[lane] = e4 / tbS[lane];
    float w[4], u[4];
    wu128(Wr, scr, r_buf, lane, w, u);
#pragma unroll
    for (int l = 0; l < 4; ++l) {
      const int lab = labs[341 + l];
      const float tbv = tbS[(1 + l) * 32 + lane];
      float bcv = tbv * __expf(regB[lab * 33 + lane]);
      bcv /= rsum32(bcv);
      const float e = bcv * w[l];
      ll += (double)(bcv * u[l]) + (double)(e * regB[lab * 33 + lane]);
      tbS[(1 + l) * 32 + lane] = e / tbv;
    }
  }
  __syncthreads();
  if (grp < 4) {  // d1: 4 L5 parents -> L6 children
    const int p = grp;
    r_buf[p * 32 + lane] = tbS[(1 + p) * 32 + lane];
    float w[4], u[4];
    wu128(Wr, scr, r_buf + p * 32, lane, w, u);
#pragma unroll
    for (int l = 0; l < 4; ++l) {
      const int q = p * 4 + l;
      const int lab = labs[345 + q];
      const float tbv = tbS[(5 + q) * 32 + lane];
      float bcv = tbv * __expf(regB[lab * 33 + lane]);
      bcv /= rsum32(bcv);
      const float e = bcv * w[l];
      ll += (double)(bcv * u[l]) + (double)(e * regB[lab * 33 + lane]);
      tbS[(5 + q) * 32 + lane] = e / tbv;
    }
  }
  __syncthreads();
  {  // d2: 16 L6 parents -> leaves, paired (hot path, R8-proven)
    const int p0 = grp, p1 = grp + 8;
    float* rb0 = r_buf + grp * 32;
    float* rb1 = r_buf + 256 + grp * 32;
    rb0[lane] = tbS[(5 + p0) * 32 + lane];
    rb1[lane] = tbS[(5 + p1) * 32 + lane];
    float w0[4], u0[4], w1[4], u1[4];
    wu128x2(Wr, scr, rb0, rb1, lane, w0, u0, w1, u1);
#pragma unroll
    for (int l = 0; l < 4; ++l) {
      const int q0 = p0 * 4 + l, q1 = p1 * 4 + l;
      const float lb0 = regB[labs[361 + q0] * 33 + lane];
      const float lb1 = regB[labs[361 + q1] * 33 + lane];
      const float lp = sPt[l * 33 + lane];
      float b0 = __expf(lp + lb0);
      float b1 = __expf(lp + lb1);
      float s0 = b0, s1 = b1;
      rsum32x2(s0, s1);
      b0 /= s0; b1 /= s1;
      const float e0 = b0 * w0[l], e1 = b1 * w1[l];
      ll += (double)(b0 * u0[l]) + (double)(e0 * lb0) + (double)(e0 * lp);
      ll += (double)(b1 * u1[l]) + (double)(e1 * lb1) + (double)(e1 * lp);
    }
  }

  // ---------- phase 7: partial + flag; block 85 finalizes ----------
#pragma unroll
  for (int k = 32; k >= 1; k >>= 1) ll += __shfl_xor(ll, k);
  double* rbd = (double*)r_buf;
  __syncthreads();
  if ((t & 63) == 0) rbd[t >> 6] = ll;
  __syncthreads();
  if (t == 0) {
    partd[s] = (rbd[0] + rbd[1]) + (rbd[2] + rbd[3]);
    __threadfence();
    st_flag(&wsi[IFLAGF + s]);
  }
  if (s == 85) {
    wait_flag(&wsi[IFLAGF + t]);  // thread t waits for block t's partial
    __syncthreads();
    __threadfence();
    if (t < 64) {
      double v = 0.0;
      for (int k = t; k < 256; k += 64) v += partd[k];
#pragma unroll
      for (int k = 32; k >= 1; k >>= 1) v += __shfl_xor(v, k);
      if (t == 0) out[0] = (float)v;
    }
  }
}

extern "C" void kernel_launch(void* const* d_in, const int* in_sizes, int n_in,
                              void* d_out, int out_size, void* d_ws, size_t ws_size,
                              hipStream_t stream) {
  (void)in_sizes; (void)n_in; (void)out_size; (void)ws_size;
  const int* labels = (const int*)d_in[0];
  const float* A = (const float*)d_in[1];
  const float* B = (const float*)d_in[2];
  const float* Pi = (const float*)d_in[3];
  const float* SP = (const float*)d_in[4];
  float* ws = (float*)d_ws;
  float* out = (float*)d_out;

  // Single dispatch; all sync via write-once MAGIC flags (poison-safe).
  hipLaunchKernelGGL(k_fused, dim3(256), dim3(256), 0, stream,
                     labels, A, B, Pi, SP, ws, out);
}

// Round 11
// 151.759 us; speedup vs baseline: 1.4861x; 1.4861x over previous
//
#include <hip/hip_runtime.h>

// HTMM: C=32 states, L=4 fanout, M=128 symbols, DEPTH=7.
// Level starts: {0,1,5,21,85,341,1365,5461,21845}.
// SINGLE kernel, 256 blocks x 512 threads (16 groups of 32 lanes).
// R11 = R8 algorithm (one tree barrier + per-block redundant top-up; NO flag
// chains — R10 proved them ~2x slower) with the TLP lever: 8 waves/block =
// 2 waves/SIMD so every LDS/shfl/FMA latency has a co-scheduled wave to hide
// it. amdgpu_waves_per_eu(2,2) pins the VGPR budget at 256 (R4's 512-thread
// spill was the compiler squeezing to 128 for occupancy). All ILP pairing
// dropped: TLP replaces it and lowers register pressure.

static constexpr int OFF_B4   = 0;      // level-4 betas [s*32+i] (8192 f)
static constexpr int OFF_PART = 8192;   // 256 doubles (512 f)
static constexpr int IC1      = 8704;   // 16 arrival counters, stride 32 ints
static constexpr int IROOT1   = 9216;   // arrival root counter
static constexpr int IC2      = 9248;   // 16 finalize counters, stride 32 ints
static constexpr int IROOT2   = 9760;   // finalize root counter

__device__ __forceinline__ float rsum32(float v) {
#pragma unroll
  for (int k = 1; k <= 16; k <<= 1) v += __shfl_xor(v, k);
  return v;
}
__device__ __forceinline__ void rsum32x4(float& a, float& b, float& c, float& d) {
#pragma unroll
  for (int k = 1; k <= 16; k <<= 1) {
    a += __shfl_xor(a, k); b += __shfl_xor(b, k);
    c += __shfl_xor(c, k); d += __shfl_xor(d, k);
  }
}
__device__ __forceinline__ float4 exp4f(float4 v) {
  return make_float4(__expf(v.x), __expf(v.y), __expf(v.z), __expf(v.w));
}

// tb = sum_k Wr[k]*X[k], k=0..127; X read as uniform-address float4.
__device__ __forceinline__ float dot128(const float* Wr, const float* X) {
  float t0 = 0.f, t1 = 0.f, t2 = 0.f, t3 = 0.f;
#pragma unroll
  for (int j = 0; j < 32; ++j) {
    const float4 x = *(const float4*)(X + j * 4);
    t0 = fmaf(Wr[4 * j + 0], x.x, t0);
    t1 = fmaf(Wr[4 * j + 1], x.y, t1);
    t2 = fmaf(Wr[4 * j + 2], x.z, t2);
    t3 = fmaf(Wr[4 * j + 3], x.w, t3);
  }
  return (t0 + t1) + (t2 + t3);
}

// w[l] = sum_i ASP[i,j=lane,l]*r[i] (Wr regs), u[l] = sum_i ALG[i,j=lane,l]*r[i].
__device__ __forceinline__ void wu128(const float* Wr, const float* ALG,
                                      const float* rb, int lane,
                                      float w[4], float u[4]) {
  w[0] = w[1] = w[2] = w[3] = 0.f;
  u[0] = u[1] = u[2] = u[3] = 0.f;
#pragma unroll
  for (int ii = 0; ii < 32; ii += 4) {
    const float4 rv = *(const float4*)(rb + ii);
#pragma unroll
    for (int di = 0; di < 4; ++di) {
      const int i = ii + di;
      const float rr = (di == 0) ? rv.x : (di == 1) ? rv.y : (di == 2) ? rv.z : rv.w;
      const float4 av = *(const float4*)(ALG + i * 128 + lane * 4);
      w[0] = fmaf(Wr[i * 4 + 0], rr, w[0]); u[0] = fmaf(av.x, rr, u[0]);
      w[1] = fmaf(Wr[i * 4 + 1], rr, w[1]); u[1] = fmaf(av.y, rr, u[1]);
      w[2] = fmaf(Wr[i * 4 + 2], rr, w[2]); u[2] = fmaf(av.z, rr, u[2]);
      w[3] = fmaf(Wr[i * 4 + 3], rr, w[3]); u[3] = fmaf(av.w, rr, u[3]);
    }
  }
}
// Path walk: w only.
__device__ __forceinline__ void wonly128(const float* Wr, const float* rb,
                                         float w[4]) {
  w[0] = w[1] = w[2] = w[3] = 0.f;
#pragma unroll
  for (int ii = 0; ii < 32; ii += 4) {
    const float4 rv = *(const float4*)(rb + ii);
#pragma unroll
    for (int di = 0; di < 4; ++di) {
      const int i = ii + di;
      const float rr = (di == 0) ? rv.x : (di == 1) ? rv.y : (di == 2) ? rv.z : rv.w;
      w[0] = fmaf(Wr[i * 4 + 0], rr, w[0]);
      w[1] = fmaf(Wr[i * 4 + 1], rr, w[1]);
      w[2] = fmaf(Wr[i * 4 + 2], rr, w[2]);
      w[3] = fmaf(Wr[i * 4 + 3], rr, w[3]);
    }
  }
}

__global__ __launch_bounds__(512)
__attribute__((amdgpu_waves_per_eu(2, 2)))
void k_fused(const int* __restrict__ labels,
             const float* __restrict__ A,
             const float* __restrict__ B,
             const float* __restrict__ Pi,
             const float* __restrict__ SP,
             float* __restrict__ ws,
             float* __restrict__ out) {
  __shared__ __align__(16) float scr[4224];
  __shared__ __align__(16) float regB[4224];
  __shared__ __align__(16) float sPt[132];
  __shared__ __align__(16) float tbrT[2720];  // top t_beta -> r in place
  __shared__ __align__(16) float tbS[672];
  __shared__ __align__(16) float ownb[32];
  __shared__ __align__(16) float r_buf[512];
  __shared__ int labs[425];
  __shared__ int fin;
  const int t = threadIdx.x, lane = t & 31, grp = t >> 5;  // 16 groups
  const int s = blockIdx.x;
  int* wsi = (int*)ws;
  double* partd = (double*)(ws + OFF_PART);
  const float4* A4 = (const float4*)A;
  const float4* B4 = (const float4*)B;

  // ---------- phase 1: softmax tables ----------
  const float sv0 = SP[0], sv1 = SP[1], sv2 = SP[2], sv3 = SP[3];
  const float sp0 = __expf(sv0), sp1 = __expf(sv1), sp2 = __expf(sv2), sp3 = __expf(sv3);
  const float spsum = sp0 + sp1 + sp2 + sp3;
  const float spinv = 1.f / spsum;
  const float lss = __logf(spsum);
  float4 c4 = make_float4(0.f, 0.f, 0.f, 0.f);
  for (int i = 0; i < 32; ++i) {
    const float4 e = exp4f(A4[i * 32 + lane]);
    c4.x += e.x; c4.y += e.y; c4.z += e.z; c4.w += e.w;
  }
  const float4 inv4 = make_float4(sp0 * spinv / c4.x, sp1 * spinv / c4.y,
                                  sp2 * spinv / c4.z, sp3 * spinv / c4.w);
  const float4 sub4 = make_float4(__logf(c4.x) - (sv0 - lss), __logf(c4.y) - (sv1 - lss),
                                  __logf(c4.z) - (sv2 - lss), __logf(c4.w) - (sv3 - lss));
#pragma unroll
  for (int k = 0; k < 2; ++k) {  // asp (up layout, stride 132)
    const int i = grp * 2 + k;
    const float4 e = exp4f(A4[i * 32 + lane]);
    *(float4*)(scr + i * 132 + 4 * lane) =
        make_float4(e.x * inv4.x, e.y * inv4.y, e.z * inv4.z, e.w * inv4.w);
  }
#pragma unroll
  for (int rI = 0; rI < 2; ++rI) {  // smB^T
    const int i = grp + rI * 16;
    const float4 e = exp4f(B4[i * 32 + lane]);
    const float sinv = 1.f / rsum32(e.x + e.y + e.z + e.w);
    regB[(4 * lane + 0) * 33 + i] = e.x * sinv;
    regB[(4 * lane + 1) * 33 + i] = e.y * sinv;
    regB[(4 * lane + 2) * 33 + i] = e.z * sinv;
    regB[(4 * lane + 3) * 33 + i] = e.w * sinv;
  }
  if (grp < 4) {  // smPi^T
    const float e = __expf(Pi[lane * 4 + grp]);
    sPt[grp * 33 + lane] = e / rsum32(e);
  }
  for (int idx = t; idx < 341; idx += 512) labs[idx] = labels[idx];
  if (t < 84) {
    int g, d;
    if (t < 4) { g = 341 + 4 * s + t; d = 341 + t; }
    else if (t < 20) { g = 1365 + 16 * s + (t - 4); d = 345 + (t - 4); }
    else { g = 5461 + 64 * s + (t - 20); d = 361 + (t - 20); }
    labs[d] = labels[g];
  }
  __syncthreads();
  float Wr[128];  // up orientation: lane = state i; Wr[4j+l] = ASP[i,j,l]
#pragma unroll
  for (int j = 0; j < 32; ++j) {
    const float4 v = *(const float4*)(scr + lane * 132 + j * 4);
    Wr[4 * j] = v.x; Wr[4 * j + 1] = v.y; Wr[4 * j + 2] = v.z; Wr[4 * j + 3] = v.w;
  }
  __syncthreads();

  // ---------- phase 2: subtree up sweep ----------
  {  // S1: 64 leaves, 4 per group (leaf pos = q&3 = grp&3 for all h)
    const int q0 = grp, q1 = grp + 16, q2 = grp + 32, q3 = grp + 48;
    float v0 = sPt[(q0 & 3) * 33 + lane] * regB[labs[361 + q0] * 33 + lane];
    float v1 = sPt[(q1 & 3) * 33 + lane] * regB[labs[361 + q1] * 33 + lane];
    float v2 = sPt[(q2 & 3) * 33 + lane] * regB[labs[361 + q2] * 33 + lane];
    float v3 = sPt[(q3 & 3) * 33 + lane] * regB[labs[361 + q3] * 33 + lane];
    float s0 = v0, s1 = v1, s2 = v2, s3 = v3;
    rsum32x4(s0, s1, s2, s3);
    scr[(q0 >> 2) * 128 + lane * 4 + (q0 & 3)] = v0 / s0;
    scr[(q1 >> 2) * 128 + lane * 4 + (q1 & 3)] = v1 / s1;
    scr[(q2 >> 2) * 128 + lane * 4 + (q2 & 3)] = v2 / s2;
    scr[(q3 >> 2) * 128 + lane * 4 + (q3 & 3)] = v3 / s3;
  }
  __syncthreads();
  {  // S2: 16 L6 parents, one per group
    const int p = grp;
    const float tb = dot128(Wr, scr + p * 128);
    float bl = tb * regB[labs[345 + p] * 33 + lane];
    bl /= rsum32(bl);
    tbS[(5 + p) * 32 + lane] = tb;
    scr[2048 + (p >> 2) * 128 + lane * 4 + (p & 3)] = bl;  // X6
  }
  __syncthreads();
  if (grp < 4) {  // S3: 4 L5 parents
    const float tb = dot128(Wr, scr + 2048 + grp * 128);
    float bl = tb * regB[labs[341 + grp] * 33 + lane];
    bl /= rsum32(bl);
    tbS[(1 + grp) * 32 + lane] = tb;
    scr[2560 + lane * 4 + grp] = bl;  // X5
  }
  __syncthreads();
  if (grp == 0) {  // S4: own level-4 root; publish b4
    const float tb = dot128(Wr, scr + 2560);
    float bl = tb * regB[labs[85 + s] * 33 + lane];
    bl /= rsum32(bl);
    tbS[lane] = tb;
    ownb[lane] = bl;
    ws[OFF_B4 + s * 32 + lane] = bl;
  }
  __syncthreads();

  // ---------- tree barrier (16 groups of 16, spread cache lines) ----------
  if (t == 0) {
    __threadfence();
    if (atomicAdd(&wsi[IC1 + 32 * (s >> 4)], 1) == 15)
      atomicAdd(&wsi[IROOT1], 1);
    while (__hip_atomic_load(&wsi[IROOT1], __ATOMIC_ACQUIRE,
                             __HIP_MEMORY_SCOPE_AGENT) < 16)
      __builtin_amdgcn_s_sleep(1);
  }
  __syncthreads();
  __threadfence();

  // ---------- phase 3: top up sweep (redundant per block) ----------
#pragma unroll
  for (int k = 0; k < 4; ++k) {  // U1: 64 L3 parents, 4 rounds of 16
    const int p = grp + 16 * k;
    float* st = scr + grp * 128;  // group-private staging (same-wave WAR safe)
#pragma unroll
    for (int l = 0; l < 4; ++l)
      st[lane * 4 + l] = ws[OFF_B4 + (p * 4 + l) * 32 + lane];
    const float tb = dot128(Wr, st);
    float bl = tb * regB[labs[21 + p] * 33 + lane];
    bl /= rsum32(bl);
    tbrT[(21 + p) * 32 + lane] = tb;
    scr[2048 + (p >> 2) * 128 + lane * 4 + (p & 3)] = bl;  // bX3
  }
  __syncthreads();
  {  // U2: 16 L2 parents, one per group
    const int p = grp;
    const float tb = dot128(Wr, scr + 2048 + p * 128);
    float bl = tb * regB[labs[5 + p] * 33 + lane];
    bl /= rsum32(bl);
    tbrT[(5 + p) * 32 + lane] = tb;
    scr[1024 + (p >> 2) * 128 + lane * 4 + (p & 3)] = bl;  // bX2 (staging dead)
  }
  __syncthreads();
  if (grp < 4) {  // U3: 4 L1 parents
    const float tb = dot128(Wr, scr + 1024 + grp * 128);
    float bl = tb * regB[labs[1 + grp] * 33 + lane];
    bl /= rsum32(bl);
    tbrT[(1 + grp) * 32 + lane] = tb;
    scr[1536 + lane * 4 + grp] = bl;  // bX1
  }
  __syncthreads();
  if (grp == 0) tbrT[lane] = dot128(Wr, scr + 1536);  // root tb
  __syncthreads();

  // ---------- phase 4: transition to down tables ----------
  for (int idx = t; idx < 4224; idx += 512) regB[idx] = __logf(regB[idx]);
  if (t < 132) sPt[t] = __logf(sPt[t]);
#pragma unroll
  for (int i = 0; i < 32; ++i) {  // Wr -> down orient (lane=j); scr -> ALG
    const float4 av = A4[i * 32 + lane];
    const float4 e = exp4f(av);
    const float4 asp = make_float4(e.x * inv4.x, e.y * inv4.y, e.z * inv4.z, e.w * inv4.w);
    Wr[i * 4 + 0] = asp.x; Wr[i * 4 + 1] = asp.y;
    Wr[i * 4 + 2] = asp.z; Wr[i * 4 + 3] = asp.w;
    if (grp == (i >> 1))
      *(float4*)(scr + i * 128 + lane * 4) =
          make_float4(asp.x * (av.x - sub4.x), asp.y * (av.y - sub4.y),
                      asp.z * (av.z - sub4.z), asp.w * (av.w - sub4.w));
  }
  __syncthreads();

  // ---------- phase 5: top down ----------
  double ll = 0.0;
  float eps4own = 0.f;  // valid in grp 0
  if (s == 0) {
    // full top-down with ll terms (block 0 only; betas recomputed from tb)
    if (grp == 0) {  // D0: root
      const float tb0 = tbrT[lane];
      float bc = tb0 * __expf(regB[labs[0] * 33 + lane]);
      bc /= rsum32(bc);
      ll += (double)(bc * regB[labs[0] * 33 + lane]);
      r_buf[lane] = bc / tb0;
      float w[4], u[4];
      wu128(Wr, scr, r_buf, lane, w, u);
#pragma unroll
      for (int l = 0; l < 4; ++l) {
        const int cl = 1 + l;
        const float tbv = tbrT[cl * 32 + lane];
        float bcv = tbv * __expf(regB[labs[cl] * 33 + lane]);
        bcv /= rsum32(bcv);
        const float e = bcv * w[l];
        ll += (double)(bcv * u[l]) + (double)(e * regB[labs[cl] * 33 + lane]);
        tbrT[cl * 32 + lane] = e / tbv;  // tb -> r
      }
    }
    __syncthreads();
    if (grp < 4) {  // D1: 4 L1 parents
      const int p = grp;
      r_buf[p * 32 + lane] = tbrT[(1 + p) * 32 + lane];
      float w[4], u[4];
      wu128(Wr, scr, r_buf + p * 32, lane, w, u);
#pragma unroll
      for (int l = 0; l < 4; ++l) {
        const int cl = 5 + p * 4 + l;
        const float tbv = tbrT[cl * 32 + lane];
        float bcv = tbv * __expf(regB[labs[cl] * 33 + lane]);
        bcv /= rsum32(bcv);
        const float e = bcv * w[l];
        ll += (double)(bcv * u[l]) + (double)(e * regB[labs[cl] * 33 + lane]);
        tbrT[cl * 32 + lane] = e / tbv;
      }
    }
    __syncthreads();
    {  // D2: 16 L2 parents, one per group
      const int p = grp;
      r_buf[grp * 32 + lane] = tbrT[(5 + p) * 32 + lane];
      float w[4], u[4];
      wu128(Wr, scr, r_buf + grp * 32, lane, w, u);
#pragma unroll
      for (int l = 0; l < 4; ++l) {
        const int cl = 21 + p * 4 + l;
        const float tbv = tbrT[cl * 32 + lane];
        float bcv = tbv * __expf(regB[labs[cl] * 33 + lane]);
        bcv /= rsum32(bcv);
        const float e = bcv * w[l];
        ll += (double)(bcv * u[l]) + (double)(e * regB[labs[cl] * 33 + lane]);
        tbrT[cl * 32 + lane] = e / tbv;
      }
    }
    __syncthreads();
#pragma unroll
    for (int k = 0; k < 4; ++k) {  // D3: 64 L3 parents; children = b4
      const int p = grp + 16 * k;
      r_buf[grp * 32 + lane] = tbrT[(21 + p) * 32 + lane];
      float w[4], u[4];
      wu128(Wr, scr, r_buf + grp * 32, lane, w, u);
#pragma unroll
      for (int l = 0; l < 4; ++l) {
        const int ci = p * 4 + l;
        const float bcv = ws[OFF_B4 + ci * 32 + lane];
        const float e = bcv * w[l];
        ll += (double)(bcv * u[l]) + (double)(e * regB[labs[85 + ci] * 33 + lane]);
        if (ci == 0) eps4own = e;  // own (s=0) level-4 eps, grp 0
      }
    }
    __syncthreads();
  } else {
    // path-only walk (all groups redundantly)
    const int n1 = 1 + (s >> 6), n2 = 5 + (s >> 4), n3 = 21 + (s >> 2);
    const int a0 = s >> 6, a1 = (s >> 4) & 3, a2 = (s >> 2) & 3, a3 = s & 3;
    float w[4];
    float tbv = tbrT[lane];
    float bcv = tbv * __expf(regB[labs[0] * 33 + lane]);
    bcv /= rsum32(bcv);
    float r = bcv / tbv;
    r_buf[grp * 32 + lane] = r;
    wonly128(Wr, r_buf + grp * 32, w);
    tbv = tbrT[n1 * 32 + lane];
    bcv = tbv * __expf(regB[labs[n1] * 33 + lane]);
    bcv /= rsum32(bcv);
    r = (bcv * w[a0]) / tbv;
    r_buf[grp * 32 + lane] = r;
    wonly128(Wr, r_buf + grp * 32, w);
    tbv = tbrT[n2 * 32 + lane];
    bcv = tbv * __expf(regB[labs[n2] * 33 + lane]);
    bcv /= rsum32(bcv);
    r = (bcv * w[a1]) / tbv;
    r_buf[grp * 32 + lane] = r;
    wonly128(Wr, r_buf + grp * 32, w);
    tbv = tbrT[n3 * 32 + lane];
    bcv = tbv * __expf(regB[labs[n3] * 33 + lane]);
    bcv /= rsum32(bcv);
    r = (bcv * w[a2]) / tbv;
    r_buf[grp * 32 + lane] = r;
    wonly128(Wr, r_buf + grp * 32, w);
    eps4own = ownb[lane] * w[a3];
    __syncthreads();
  }

  // ---------- phase 6: subtree down sweep ----------
  if (grp == 0) {  // d0: own L4 node -> L5 children
    r_buf[lane] = eps4own / tbS[lane];
    float w[4], u[4];
    wu128(Wr, scr, r_buf, lane, w, u);
#pragma unroll
    for (int l = 0; l < 4; ++l) {
      const int lab = labs[341 + l];
      const float tbv = tbS[(1 + l) * 32 + lane];
      float bcv = tbv * __expf(regB[lab * 33 + lane]);
      bcv /= rsum32(bcv);
      const float e = bcv * w[l];
      ll += (double)(bcv * u[l]) + (double)(e * regB[lab * 33 + lane]);
      tbS[(1 + l) * 32 + lane] = e / tbv;
    }
  }
  __syncthreads();
  if (grp < 4) {  // d1: 4 L5 parents -> L6 children
    const int p = grp;
    r_buf[p * 32 + lane] = tbS[(1 + p) * 32 + lane];
    float w[4], u[4];
    wu128(Wr, scr, r_buf + p * 32, lane, w, u);
#pragma unroll
    for (int l = 0; l < 4; ++l) {
      const int q = p * 4 + l;
      const int lab = labs[345 + q];
      const float tbv = tbS[(5 + q) * 32 + lane];
      float bcv = tbv * __expf(regB[lab * 33 + lane]);
      bcv /= rsum32(bcv);
      const float e = bcv * w[l];
      ll += (double)(bcv * u[l]) + (double)(e * regB[lab * 33 + lane]);
      tbS[(5 + q) * 32 + lane] = e / tbv;
    }
  }
  __syncthreads();
  {  // d2: 16 L6 parents -> leaves, one per group
    const int p = grp;
    float* rb = r_buf + grp * 32;
    rb[lane] = tbS[(5 + p) * 32 + lane];
    float w[4], u[4];
    wu128(Wr, scr, rb, lane, w, u);
#pragma unroll
    for (int l = 0; l < 4; ++l) {
      const int q = p * 4 + l;
      const float lb = regB[labs[361 + q] * 33 + lane];
      const float lp = sPt[l * 33 + lane];
      float bcv = __expf(lp + lb);
      bcv /= rsum32(bcv);
      const float e = bcv * w[l];
      ll += (double)(bcv * u[l]) + (double)(e * lb) + (double)(e * lp);
    }
  }

  // ---------- phase 7: partials + tree finalize ----------
#pragma unroll
  for (int k = 32; k >= 1; k >>= 1) ll += __shfl_xor(ll, k);
  double* rbd = (double*)r_buf;
  __syncthreads();
  if ((t & 63) == 0) rbd[t >> 6] = ll;  // 8 wave partials
  __syncthreads();
  if (t == 0) {
    double bsum = 0.0;
#pragma unroll
    for (int k = 0; k < 8; ++k) bsum += rbd[k];
    partd[s] = bsum;
    __threadfence();
    int f = 0;
    if (atomicAdd(&wsi[IC2 + 32 * (s >> 4)], 1) == 15)
      if (atomicAdd(&wsi[IROOT2], 1) == 15) f = 1;
    fin = f;
  }
  __syncthreads();
  if (fin) {  // last block: all partials visible
    __threadfence();
    if (t < 64) {
      double v = 0.0;
      for (int k = t; k < 256; k += 64) v += partd[k];
#pragma unroll
      for (int k = 32; k >= 1; k >>= 1) v += __shfl_xor(v, k);
      if (t == 0) out[0] = (float)v;
    }
  }
}

extern "C" void kernel_launch(void* const* d_in, const int* in_sizes, int n_in,
                              void* d_out, int out_size, void* d_ws, size_t ws_size,
                              hipStream_t stream) {
  (void)in_sizes; (void)n_in; (void)out_size; (void)ws_size;
  const int* labels = (const int*)d_in[0];
  const float* A = (const float*)d_in[1];
  const float* B = (const float*)d_in[2];
  const float* Pi = (const float*)d_in[3];
  const float* SP = (const float*)d_in[4];
  float* ws = (float*)d_ws;
  float* out = (float*)d_out;

  // zero the counter region (ints IC1..IROOT2: [8704, 9761) * 4 bytes)
  hipMemsetAsync((char*)d_ws + IC1 * 4, 0, (IROOT2 + 1 - IC1) * 4, stream);
  hipLaunchKernelGGL(k_fused, dim3(256), dim3(512), 0, stream,
                     labels, A, B, Pi, SP, ws, out);
}

// Round 12
// 143.401 us; speedup vs baseline: 1.5727x; 1.0583x over previous
//
#include <hip/hip_runtime.h>

// HTMM: C=32 states, L=4 fanout, M=128 symbols, DEPTH=7.
// Level starts: {0,1,5,21,85,341,1365,5461,21845}.
// SINGLE kernel, 256 blocks x 256 threads, one block per level-4 subtree.
// R12 = R8 (best: 89.7 us kernel, 248 VGPR no-spill) with ONE change:
// the tree barrier's spin uses atomic RMW polls (atomicAdd(p,0)) instead of
// __hip_atomic_load. Theory: per-XCD L2s are not cross-coherent; a plain/
// acquire load poll can be served from a stale clean L2 line until eviction
// (~16 us per flag hop, measured via R10's +80 us flag chain). RMW executes
// at the device coherence point. Fan-out release words (16 pollers per line)
// avoid a 256-way RMW train on one address.

static constexpr int OFF_B4   = 0;      // level-4 betas [s*32+i] (8192 f)
static constexpr int OFF_PART = 8192;   // 256 doubles (512 f)
static constexpr int IC1      = 8704;   // 16 arrival counters, stride 32 ints
static constexpr int IROOT1   = 9216;   // arrival root counter
static constexpr int IREL     = 9248;   // 16 release words, stride 32 ints
static constexpr int IC2      = 9760;   // 16 finalize counters, stride 32 ints
static constexpr int IROOT2   = 10272;  // finalize root counter
static constexpr int MAGIC    = 0x5CA1AB1E;

__device__ __forceinline__ float rsum32(float v) {
#pragma unroll
  for (int k = 1; k <= 16; k <<= 1) v += __shfl_xor(v, k);
  return v;
}
__device__ __forceinline__ void rsum32x2(float& a, float& b) {
#pragma unroll
  for (int k = 1; k <= 16; k <<= 1) { a += __shfl_xor(a, k); b += __shfl_xor(b, k); }
}
__device__ __forceinline__ void rsum32x4(float& a, float& b, float& c, float& d) {
#pragma unroll
  for (int k = 1; k <= 16; k <<= 1) {
    a += __shfl_xor(a, k); b += __shfl_xor(b, k);
    c += __shfl_xor(c, k); d += __shfl_xor(d, k);
  }
}
__device__ __forceinline__ float4 exp4f(float4 v) {
  return make_float4(__expf(v.x), __expf(v.y), __expf(v.z), __expf(v.w));
}

__device__ __forceinline__ float dot128(const float* Wr, const float* X) {
  float t0 = 0.f, t1 = 0.f, t2 = 0.f, t3 = 0.f;
#pragma unroll
  for (int j = 0; j < 32; ++j) {
    const float4 x = *(const float4*)(X + j * 4);
    t0 = fmaf(Wr[4 * j + 0], x.x, t0);
    t1 = fmaf(Wr[4 * j + 1], x.y, t1);
    t2 = fmaf(Wr[4 * j + 2], x.z, t2);
    t3 = fmaf(Wr[4 * j + 3], x.w, t3);
  }
  return (t0 + t1) + (t2 + t3);
}
// Two parents, shared Wr: 8 independent FMA chains, 2 LDS streams.
__device__ __forceinline__ void dot128x2(const float* Wr, const float* X0,
                                         const float* X1, float& o0, float& o1) {
  float a0 = 0.f, a1 = 0.f, a2 = 0.f, a3 = 0.f;
  float b0 = 0.f, b1 = 0.f, b2 = 0.f, b3 = 0.f;
#pragma unroll
  for (int j = 0; j < 32; ++j) {
    const float4 x = *(const float4*)(X0 + j * 4);
    const float4 y = *(const float4*)(X1 + j * 4);
    a0 = fmaf(Wr[4 * j + 0], x.x, a0); b0 = fmaf(Wr[4 * j + 0], y.x, b0);
    a1 = fmaf(Wr[4 * j + 1], x.y, a1); b1 = fmaf(Wr[4 * j + 1], y.y, b1);
    a2 = fmaf(Wr[4 * j + 2], x.z, a2); b2 = fmaf(Wr[4 * j + 2], y.z, b2);
    a3 = fmaf(Wr[4 * j + 3], x.w, a3); b3 = fmaf(Wr[4 * j + 3], y.w, b3);
  }
  o0 = (a0 + a1) + (a2 + a3);
  o1 = (b0 + b1) + (b2 + b3);
}

__device__ __forceinline__ void wu128(const float* Wr, const float* ALG,
                                      const float* rb, int lane,
                                      float w[4], float u[4]) {
  w[0] = w[1] = w[2] = w[3] = 0.f;
  u[0] = u[1] = u[2] = u[3] = 0.f;
#pragma unroll
  for (int ii = 0; ii < 32; ii += 4) {
    const float4 rv = *(const float4*)(rb + ii);
#pragma unroll
    for (int di = 0; di < 4; ++di) {
      const int i = ii + di;
      const float rr = (di == 0) ? rv.x : (di == 1) ? rv.y : (di == 2) ? rv.z : rv.w;
      const float4 av = *(const float4*)(ALG + i * 128 + lane * 4);
      w[0] = fmaf(Wr[i * 4 + 0], rr, w[0]); u[0] = fmaf(av.x, rr, u[0]);
      w[1] = fmaf(Wr[i * 4 + 1], rr, w[1]); u[1] = fmaf(av.y, rr, u[1]);
      w[2] = fmaf(Wr[i * 4 + 2], rr, w[2]); u[2] = fmaf(av.z, rr, u[2]);
      w[3] = fmaf(Wr[i * 4 + 3], rr, w[3]); u[3] = fmaf(av.w, rr, u[3]);
    }
  }
}
// Two parents share the SAME ALG ds_read_b128 stream (2x FLOP per LDS read).
__device__ __forceinline__ void wu128x2(const float* Wr, const float* ALG,
                                        const float* rb0, const float* rb1, int lane,
                                        float w0[4], float u0[4],
                                        float w1[4], float u1[4]) {
#pragma unroll
  for (int l = 0; l < 4; ++l) { w0[l] = u0[l] = w1[l] = u1[l] = 0.f; }
#pragma unroll
  for (int ii = 0; ii < 32; ii += 4) {
    const float4 r0 = *(const float4*)(rb0 + ii);
    const float4 r1 = *(const float4*)(rb1 + ii);
#pragma unroll
    for (int di = 0; di < 4; ++di) {
      const int i = ii + di;
      const float q0 = (di == 0) ? r0.x : (di == 1) ? r0.y : (di == 2) ? r0.z : r0.w;
      const float q1 = (di == 0) ? r1.x : (di == 1) ? r1.y : (di == 2) ? r1.z : r1.w;
      const float4 av = *(const float4*)(ALG + i * 128 + lane * 4);
      w0[0] = fmaf(Wr[i * 4 + 0], q0, w0[0]); w1[0] = fmaf(Wr[i * 4 + 0], q1, w1[0]);
      u0[0] = fmaf(av.x, q0, u0[0]);          u1[0] = fmaf(av.x, q1, u1[0]);
      w0[1] = fmaf(Wr[i * 4 + 1], q0, w0[1]); w1[1] = fmaf(Wr[i * 4 + 1], q1, w1[1]);
      u0[1] = fmaf(av.y, q0, u0[1]);          u1[1] = fmaf(av.y, q1, u1[1]);
      w0[2] = fmaf(Wr[i * 4 + 2], q0, w0[2]); w1[2] = fmaf(Wr[i * 4 + 2], q1, w1[2]);
      u0[2] = fmaf(av.z, q0, u0[2]);          u1[2] = fmaf(av.z, q1, u1[2]);
      w0[3] = fmaf(Wr[i * 4 + 3], q0, w0[3]); w1[3] = fmaf(Wr[i * 4 + 3], q1, w1[3]);
      u0[3] = fmaf(av.w, q0, u0[3]);          u1[3] = fmaf(av.w, q1, u1[3]);
    }
  }
}
// Path walk: w only.
__device__ __forceinline__ void wonly128(const float* Wr, const float* rb,
                                         float w[4]) {
  w[0] = w[1] = w[2] = w[3] = 0.f;
#pragma unroll
  for (int ii = 0; ii < 32; ii += 4) {
    const float4 rv = *(const float4*)(rb + ii);
#pragma unroll
    for (int di = 0; di < 4; ++di) {
      const int i = ii + di;
      const float rr = (di == 0) ? rv.x : (di == 1) ? rv.y : (di == 2) ? rv.z : rv.w;
      w[0] = fmaf(Wr[i * 4 + 0], rr, w[0]);
      w[1] = fmaf(Wr[i * 4 + 1], rr, w[1]);
      w[2] = fmaf(Wr[i * 4 + 2], rr, w[2]);
      w[3] = fmaf(Wr[i * 4 + 3], rr, w[3]);
    }
  }
}

__global__ __launch_bounds__(256, 1) void k_fused(const int* __restrict__ labels,
                                                  const float* __restrict__ A,
                                                  const float* __restrict__ B,
                                                  const float* __restrict__ Pi,
                                                  const float* __restrict__ SP,
                                                  float* __restrict__ ws,
                                                  float* __restrict__ out) {
  __shared__ __align__(16) float scr[4224];
  __shared__ __align__(16) float regB[4224];
  __shared__ __align__(16) float sPt[132];
  __shared__ __align__(16) float tbrT[2720];
  __shared__ __align__(16) float tbS[672];
  __shared__ __align__(16) float ownb[32];
  __shared__ __align__(16) float r_buf[512];
  __shared__ int labs[425];
  __shared__ int fin;
  const int t = threadIdx.x, lane = t & 31, grp = t >> 5;  // 8 groups
  const int s = blockIdx.x;
  int* wsi = (int*)ws;
  double* partd = (double*)(ws + OFF_PART);
  const float4* A4 = (const float4*)A;
  const float4* B4 = (const float4*)B;

  // ---------- phase 1: softmax tables ----------
  const float sv0 = SP[0], sv1 = SP[1], sv2 = SP[2], sv3 = SP[3];
  const float sp0 = __expf(sv0), sp1 = __expf(sv1), sp2 = __expf(sv2), sp3 = __expf(sv3);
  const float spsum = sp0 + sp1 + sp2 + sp3;
  const float spinv = 1.f / spsum;
  const float lss = __logf(spsum);
  float4 c4 = make_float4(0.f, 0.f, 0.f, 0.f);
  for (int i = 0; i < 32; ++i) {
    const float4 e = exp4f(A4[i * 32 + lane]);
    c4.x += e.x; c4.y += e.y; c4.z += e.z; c4.w += e.w;
  }
  const float4 inv4 = make_float4(sp0 * spinv / c4.x, sp1 * spinv / c4.y,
                                  sp2 * spinv / c4.z, sp3 * spinv / c4.w);
  const float4 sub4 = make_float4(__logf(c4.x) - (sv0 - lss), __logf(c4.y) - (sv1 - lss),
                                  __logf(c4.z) - (sv2 - lss), __logf(c4.w) - (sv3 - lss));
#pragma unroll
  for (int k = 0; k < 4; ++k) {  // asp (up layout, stride 132)
    const int i = grp * 4 + k;
    const float4 e = exp4f(A4[i * 32 + lane]);
    *(float4*)(scr + i * 132 + 4 * lane) =
        make_float4(e.x * inv4.x, e.y * inv4.y, e.z * inv4.z, e.w * inv4.w);
  }
#pragma unroll
  for (int rI = 0; rI < 4; ++rI) {  // smB^T
    const int i = grp + rI * 8;
    const float4 e = exp4f(B4[i * 32 + lane]);
    const float sinv = 1.f / rsum32(e.x + e.y + e.z + e.w);
    regB[(4 * lane + 0) * 33 + i] = e.x * sinv;
    regB[(4 * lane + 1) * 33 + i] = e.y * sinv;
    regB[(4 * lane + 2) * 33 + i] = e.z * sinv;
    regB[(4 * lane + 3) * 33 + i] = e.w * sinv;
  }
  if (grp < 4) {  // smPi^T
    const float e = __expf(Pi[lane * 4 + grp]);
    sPt[grp * 33 + lane] = e / rsum32(e);
  }
  for (int idx = t; idx < 341; idx += 256) labs[idx] = labels[idx];
  if (t < 84) {
    int g, d;
    if (t < 4) { g = 341 + 4 * s + t; d = 341 + t; }
    else if (t < 20) { g = 1365 + 16 * s + (t - 4); d = 345 + (t - 4); }
    else { g = 5461 + 64 * s + (t - 20); d = 361 + (t - 20); }
    labs[d] = labels[g];
  }
  __syncthreads();
  float Wr[128];  // up orientation
#pragma unroll
  for (int j = 0; j < 32; ++j) {
    const float4 v = *(const float4*)(scr + lane * 132 + j * 4);
    Wr[4 * j] = v.x; Wr[4 * j + 1] = v.y; Wr[4 * j + 2] = v.z; Wr[4 * j + 3] = v.w;
  }
  __syncthreads();

  // ---------- phase 2: subtree up sweep ----------
#pragma unroll
  for (int h = 0; h < 2; ++h) {  // S1: 64 leaves, batches of 4
    const int q0 = grp + 32 * h, q1 = q0 + 8, q2 = q0 + 16, q3 = q0 + 24;
    float v0 = sPt[(q0 & 3) * 33 + lane] * regB[labs[361 + q0] * 33 + lane];
    float v1 = sPt[(q1 & 3) * 33 + lane] * regB[labs[361 + q1] * 33 + lane];
    float v2 = sPt[(q2 & 3) * 33 + lane] * regB[labs[361 + q2] * 33 + lane];
    float v3 = sPt[(q3 & 3) * 33 + lane] * regB[labs[361 + q3] * 33 + lane];
    float s0 = v0, s1 = v1, s2 = v2, s3 = v3;
    rsum32x4(s0, s1, s2, s3);
    scr[(q0 >> 2) * 128 + lane * 4 + (q0 & 3)] = v0 / s0;
    scr[(q1 >> 2) * 128 + lane * 4 + (q1 & 3)] = v1 / s1;
    scr[(q2 >> 2) * 128 + lane * 4 + (q2 & 3)] = v2 / s2;
    scr[(q3 >> 2) * 128 + lane * 4 + (q3 & 3)] = v3 / s3;
  }
  __syncthreads();
  {  // S2: 16 L6 parents, paired
    const int p0 = grp, p1 = grp + 8;
    float tb0, tb1;
    dot128x2(Wr, scr + p0 * 128, scr + p1 * 128, tb0, tb1);
    float bl0 = tb0 * regB[labs[345 + p0] * 33 + lane];
    float bl1 = tb1 * regB[labs[345 + p1] * 33 + lane];
    float s0 = bl0, s1 = bl1;
    rsum32x2(s0, s1);
    bl0 /= s0; bl1 /= s1;
    tbS[(5 + p0) * 32 + lane] = tb0;
    tbS[(5 + p1) * 32 + lane] = tb1;
    scr[2048 + (p0 >> 2) * 128 + lane * 4 + (p0 & 3)] = bl0;  // X6
    scr[2048 + (p1 >> 2) * 128 + lane * 4 + (p1 & 3)] = bl1;
  }
  __syncthreads();
  if (grp < 4) {  // S3: 4 L5 parents
    const float tb = dot128(Wr, scr + 2048 + grp * 128);
    float bl = tb * regB[labs[341 + grp] * 33 + lane];
    bl /= rsum32(bl);
    tbS[(1 + grp) * 32 + lane] = tb;
    scr[2560 + lane * 4 + grp] = bl;  // X5
  }
  __syncthreads();
  if (grp == 0) {  // S4: own level-4 root; publish b4
    const float tb = dot128(Wr, scr + 2560);
    float bl = tb * regB[labs[85 + s] * 33 + lane];
    bl /= rsum32(bl);
    tbS[lane] = tb;
    ownb[lane] = bl;
    ws[OFF_B4 + s * 32 + lane] = bl;
  }
  __syncthreads();

  // ---------- tree barrier: pure-atomic arrival + fan-out release words,
  // ----------               RMW polls (coherence-point reads) ----------
  if (t == 0) {
    __threadfence();
    if (atomicAdd(&wsi[IC1 + 32 * (s >> 4)], 1) == 15) {
      if (atomicAdd(&wsi[IROOT1], 1) == 15) {
        // last arriver releases all 16 group lines
#pragma unroll
        for (int g = 0; g < 16; ++g) atomicExch(&wsi[IREL + 32 * g], MAGIC);
      }
    }
    while (atomicAdd(&wsi[IREL + 32 * (s >> 4)], 0) != MAGIC)
      __builtin_amdgcn_s_sleep(2);
  }
  __syncthreads();
  __threadfence();

  // ---------- phase 3: top up sweep (redundant per block), paired ----------
#pragma unroll
  for (int k = 0; k < 4; ++k) {  // 64 L3 parents: 4 paired rounds
    const int p0 = grp + 16 * k, p1 = p0 + 8;
    float* st0 = scr + grp * 128;
    float* st1 = scr + 1024 + grp * 128;
#pragma unroll
    for (int l = 0; l < 4; ++l) {
      st0[lane * 4 + l] = ws[OFF_B4 + (p0 * 4 + l) * 32 + lane];
      st1[lane * 4 + l] = ws[OFF_B4 + (p1 * 4 + l) * 32 + lane];
    }
    float tb0, tb1;
    dot128x2(Wr, st0, st1, tb0, tb1);
    float bl0 = tb0 * regB[labs[21 + p0] * 33 + lane];
    float bl1 = tb1 * regB[labs[21 + p1] * 33 + lane];
    float s0 = bl0, s1 = bl1;
    rsum32x2(s0, s1);
    bl0 /= s0; bl1 /= s1;
    tbrT[(21 + p0) * 32 + lane] = tb0;
    tbrT[(21 + p1) * 32 + lane] = tb1;
    scr[2048 + (p0 >> 2) * 128 + lane * 4 + (p0 & 3)] = bl0;  // bX3
    scr[2048 + (p1 >> 2) * 128 + lane * 4 + (p1 & 3)] = bl1;
  }
  __syncthreads();
  {  // 16 L2 parents, paired
    const int p0 = grp, p1 = grp + 8;
    float tb0, tb1;
    dot128x2(Wr, scr + 2048 + p0 * 128, scr + 2048 + p1 * 128, tb0, tb1);
    float bl0 = tb0 * regB[labs[5 + p0] * 33 + lane];
    float bl1 = tb1 * regB[labs[5 + p1] * 33 + lane];
    float s0 = bl0, s1 = bl1;
    rsum32x2(s0, s1);
    bl0 /= s0; bl1 /= s1;
    tbrT[(5 + p0) * 32 + lane] = tb0;
    tbrT[(5 + p1) * 32 + lane] = tb1;
    scr[1024 + (p0 >> 2) * 128 + lane * 4 + (p0 & 3)] = bl0;  // bX2
    scr[1024 + (p1 >> 2) * 128 + lane * 4 + (p1 & 3)] = bl1;
  }
  __syncthreads();
  if (grp < 4) {  // 4 L1 parents
    const float tb = dot128(Wr, scr + 1024 + grp * 128);
    float bl = tb * regB[labs[1 + grp] * 33 + lane];
    bl /= rsum32(bl);
    tbrT[(1 + grp) * 32 + lane] = tb;
    scr[1536 + lane * 4 + grp] = bl;  // bX1
  }
  __syncthreads();
  if (grp == 0) tbrT[lane] = dot128(Wr, scr + 1536);  // root tb
  __syncthreads();

  // ---------- phase 4: transition to down tables ----------
  for (int idx = t; idx < 4224; idx += 256) regB[idx] = __logf(regB[idx]);
  if (t < 132) sPt[t] = __logf(sPt[t]);
#pragma unroll
  for (int i = 0; i < 32; ++i) {  // Wr -> down orient (lane=j); scr -> ALG
    const float4 av = A4[i * 32 + lane];
    const float4 e = exp4f(av);
    const float4 asp = make_float4(e.x * inv4.x, e.y * inv4.y, e.z * inv4.z, e.w * inv4.w);
    Wr[i * 4 + 0] = asp.x; Wr[i * 4 + 1] = asp.y;
    Wr[i * 4 + 2] = asp.z; Wr[i * 4 + 3] = asp.w;
    if (grp == (i >> 2))
      *(float4*)(scr + i * 128 + lane * 4) =
          make_float4(asp.x * (av.x - sub4.x), asp.y * (av.y - sub4.y),
                      asp.z * (av.z - sub4.z), asp.w * (av.w - sub4.w));
  }
  __syncthreads();

  // ---------- phase 5: top down ----------
  double ll = 0.0;
  float eps4own = 0.f;  // valid in grp 0
  if (s == 0) {
    if (grp == 0) {  // D0: root
      const float tb0 = tbrT[lane];
      float bc = tb0 * __expf(regB[labs[0] * 33 + lane]);
      bc /= rsum32(bc);
      ll += (double)(bc * regB[labs[0] * 33 + lane]);
      r_buf[lane] = bc / tb0;
      float w[4], u[4];
      wu128(Wr, scr, r_buf, lane, w, u);
#pragma unroll
      for (int l = 0; l < 4; ++l) {
        const int cl = 1 + l;
        const float tbv = tbrT[cl * 32 + lane];
        float bcv = tbv * __expf(regB[labs[cl] * 33 + lane]);
        bcv /= rsum32(bcv);
        const float e = bcv * w[l];
        ll += (double)(bcv * u[l]) + (double)(e * regB[labs[cl] * 33 + lane]);
        tbrT[cl * 32 + lane] = e / tbv;
      }
    }
    __syncthreads();
    if (grp < 4) {  // D1: 4 L1 parents
      const int p = grp;
      r_buf[p * 32 + lane] = tbrT[(1 + p) * 32 + lane];
      float w[4], u[4];
      wu128(Wr, scr, r_buf + p * 32, lane, w, u);
#pragma unroll
      for (int l = 0; l < 4; ++l) {
        const int cl = 5 + p * 4 + l;
        const float tbv = tbrT[cl * 32 + lane];
        float bcv = tbv * __expf(regB[labs[cl] * 33 + lane]);
        bcv /= rsum32(bcv);
        const float e = bcv * w[l];
        ll += (double)(bcv * u[l]) + (double)(e * regB[labs[cl] * 33 + lane]);
        tbrT[cl * 32 + lane] = e / tbv;
      }
    }
    __syncthreads();
    {  // D2: 16 L2 parents, paired
      const int p0 = grp, p1 = grp + 8;
      float* rb0 = r_buf + grp * 32;
      float* rb1 = r_buf + 256 + grp * 32;
      rb0[lane] = tbrT[(5 + p0) * 32 + lane];
      rb1[lane] = tbrT[(5 + p1) * 32 + lane];
      float w0[4], u0[4], w1[4], u1[4];
      wu128x2(Wr, scr, rb0, rb1, lane, w0, u0, w1, u1);
#pragma unroll
      for (int l = 0; l < 4; ++l) {
        const int c0 = 21 + p0 * 4 + l, c1 = 21 + p1 * 4 + l;
        const float tv0 = tbrT[c0 * 32 + lane], tv1 = tbrT[c1 * 32 + lane];
        float b0 = tv0 * __expf(regB[labs[c0] * 33 + lane]);
        float b1 = tv1 * __expf(regB[labs[c1] * 33 + lane]);
        float s0 = b0, s1 = b1;
        rsum32x2(s0, s1);
        b0 /= s0; b1 /= s1;
        const float e0 = b0 * w0[l], e1 = b1 * w1[l];
        ll += (double)(b0 * u0[l]) + (double)(e0 * regB[labs[c0] * 33 + lane]);
        ll += (double)(b1 * u1[l]) + (double)(e1 * regB[labs[c1] * 33 + lane]);
        tbrT[c0 * 32 + lane] = e0 / tv0;
        tbrT[c1 * 32 + lane] = e1 / tv1;
      }
    }
    __syncthreads();
#pragma unroll
    for (int k = 0; k < 4; ++k) {  // D3: 64 L3 parents, paired; children = b4
      const int p0 = grp + 16 * k, p1 = p0 + 8;
      float* rb0 = r_buf + grp * 32;
      float* rb1 = r_buf + 256 + grp * 32;
      rb0[lane] = tbrT[(21 + p0) * 32 + lane];
      rb1[lane] = tbrT[(21 + p1) * 32 + lane];
      float w0[4], u0[4], w1[4], u1[4];
      wu128x2(Wr, scr, rb0, rb1, lane, w0, u0, w1, u1);
#pragma unroll
      for (int l = 0; l < 4; ++l) {
        const int ci0 = p0 * 4 + l, ci1 = p1 * 4 + l;
        const float bc0 = ws[OFF_B4 + ci0 * 32 + lane];
        const float bc1 = ws[OFF_B4 + ci1 * 32 + lane];
        const float e0 = bc0 * w0[l], e1 = bc1 * w1[l];
        ll += (double)(bc0 * u0[l]) + (double)(e0 * regB[labs[85 + ci0] * 33 + lane]);
        ll += (double)(bc1 * u1[l]) + (double)(e1 * regB[labs[85 + ci1] * 33 + lane]);
        if (ci0 == 0) eps4own = e0;
      }
    }
    __syncthreads();
  } else {
    // path-only walk (all groups redundantly)
    const int n1 = 1 + (s >> 6), n2 = 5 + (s >> 4), n3 = 21 + (s >> 2);
    const int a0 = s >> 6, a1 = (s >> 4) & 3, a2 = (s >> 2) & 3, a3 = s & 3;
    float w[4];
    float tbv = tbrT[lane];
    float bcv = tbv * __expf(regB[labs[0] * 33 + lane]);
    bcv /= rsum32(bcv);
    float r = bcv / tbv;
    r_buf[grp * 32 + lane] = r;
    wonly128(Wr, r_buf + grp * 32, w);
    tbv = tbrT[n1 * 32 + lane];
    bcv = tbv * __expf(regB[labs[n1] * 33 + lane]);
    bcv /= rsum32(bcv);
    r = (bcv * w[a0]) / tbv;
    r_buf[grp * 32 + lane] = r;
    wonly128(Wr, r_buf + grp * 32, w);
    tbv = tbrT[n2 * 32 + lane];
    bcv = tbv * __expf(regB[labs[n2] * 33 + lane]);
    bcv /= rsum32(bcv);
    r = (bcv * w[a1]) / tbv;
    r_buf[grp * 32 + lane] = r;
    wonly128(Wr, r_buf + grp * 32, w);
    tbv = tbrT[n3 * 32 + lane];
    bcv = tbv * __expf(regB[labs[n3] * 33 + lane]);
    bcv /= rsum32(bcv);
    r = (bcv * w[a2]) / tbv;
    r_buf[grp * 32 + lane] = r;
    wonly128(Wr, r_buf + grp * 32, w);
    eps4own = ownb[lane] * w[a3];
    __syncthreads();
  }

  // ---------- phase 6: subtree down sweep ----------
  if (grp == 0) {  // d0: own L4 node -> L5 children
    r_buf[lane] = eps4own / tbS[lane];
    float w[4], u[4];
    wu128(Wr, scr, r_buf, lane, w, u);
#pragma unroll
    for (int l = 0; l < 4; ++l) {
      const int lab = labs[341 + l];
      const float tbv = tbS[(1 + l) * 32 + lane];
      float bcv = tbv * __expf(regB[lab * 33 + lane]);
      bcv /= rsum32(bcv);
      const float e = bcv * w[l];
      ll += (double)(bcv * u[l]) + (double)(e * regB[lab * 33 + lane]);
      tbS[(1 + l) * 32 + lane] = e / tbv;
    }
  }
  __syncthreads();
  if (grp < 4) {  // d1: 4 L5 parents -> L6 children
    const int p = grp;
    r_buf[p * 32 + lane] = tbS[(1 + p) * 32 + lane];
    float w[4], u[4];
    wu128(Wr, scr, r_buf + p * 32, lane, w, u);
#pragma unroll
    for (int l = 0; l < 4; ++l) {
      const int q = p * 4 + l;
      const int lab = labs[345 + q];
      const float tbv = tbS[(5 + q) * 32 + lane];
      float bcv = tbv * __expf(regB[lab * 33 + lane]);
      bcv /= rsum32(bcv);
      const float e = bcv * w[l];
      ll += (double)(bcv * u[l]) + (double)(e * regB[lab * 33 + lane]);
      tbS[(5 + q) * 32 + lane] = e / tbv;
    }
  }
  __syncthreads();
  {  // d2: 16 L6 parents -> leaves, paired
    const int p0 = grp, p1 = grp + 8;
    float* rb0 = r_buf + grp * 32;
    float* rb1 = r_buf + 256 + grp * 32;
    rb0[lane] = tbS[(5 + p0) * 32 + lane];
    rb1[lane] = tbS[(5 + p1) * 32 + lane];
    float w0[4], u0[4], w1[4], u1[4];
    wu128x2(Wr, scr, rb0, rb1, lane, w0, u0, w1, u1);
#pragma unroll
    for (int l = 0; l < 4; ++l) {
      const int q0 = p0 * 4 + l, q1 = p1 * 4 + l;
      const float lb0 = regB[labs[361 + q0] * 33 + lane];
      const float lb1 = regB[labs[361 + q1] * 33 + lane];
      const float lp = sPt[l * 33 + lane];
      float b0 = __expf(lp + lb0);
      float b1 = __expf(lp + lb1);
      float s0 = b0, s1 = b1;
      rsum32x2(s0, s1);
      b0 /= s0; b1 /= s1;
      const float e0 = b0 * w0[l], e1 = b1 * w1[l];
      ll += (double)(b0 * u0[l]) + (double)(e0 * lb0) + (double)(e0 * lp);
      ll += (double)(b1 * u1[l]) + (double)(e1 * lb1) + (double)(e1 * lp);
    }
  }

  // ---------- phase 7: partials + tree finalize (poll-free atomics) ----------
#pragma unroll
  for (int k = 32; k >= 1; k >>= 1) ll += __shfl_xor(ll, k);
  double* rbd = (double*)r_buf;
  __syncthreads();
  if ((t & 63) == 0) rbd[t >> 6] = ll;
  __syncthreads();
  if (t == 0) {
    partd[s] = (rbd[0] + rbd[1]) + (rbd[2] + rbd[3]);
    __threadfence();
    int f = 0;
    if (atomicAdd(&wsi[IC2 + 32 * (s >> 4)], 1) == 15)
      if (atomicAdd(&wsi[IROOT2], 1) == 15) f = 1;
    fin = f;
  }
  __syncthreads();
  if (fin) {  // last block: all partials visible (first-touch reads)
    __threadfence();
    if (t < 64) {
      double v = 0.0;
      for (int k = t; k < 256; k += 64) v += partd[k];
#pragma unroll
      for (int k = 32; k >= 1; k >>= 1) v += __shfl_xor(v, k);
      if (t == 0) out[0] = (float)v;
    }
  }
}

extern "C" void kernel_launch(void* const* d_in, const int* in_sizes, int n_in,
                              void* d_out, int out_size, void* d_ws, size_t ws_size,
                              hipStream_t stream) {
  (void)in_sizes; (void)n_in; (void)out_size; (void)ws_size;
  const int* labels = (const int*)d_in[0];
  const float* A = (const float*)d_in[1];
  const float* B = (const float*)d_in[2];
  const float* Pi = (const float*)d_in[3];
  const float* SP = (const float*)d_in[4];
  float* ws = (float*)d_ws;
  float* out = (float*)d_out;

  // zero the counter region (ints IC1..IROOT2: [8704, 10273) * 4 bytes)
  hipMemsetAsync((char*)d_ws + IC1 * 4, 0, (IROOT2 + 1 - IC1) * 4, stream);
  hipLaunchKernelGGL(k_fused, dim3(256), dim3(256), 0, stream,
                     labels, A, B, Pi, SP, ws, out);
}